// Round 4
// baseline (112.558 us; speedup 1.0000x reference)
//
#include <hip/hip_runtime.h>

// HyperLayer, R4: two-phase binned scatter (R3 structure), occupancy-tuned.
// R3 evidence: kernels now below the harness's 42us d_ws-poison fills in the
// top-5; remaining ~50us of kernel time vs ~15us traffic floor => latency-
// bound. R3 ran phase1 at 245 blocks (1/CU, 8 waves) and phase2 at 4 waves/CU.
// R4: phase1 977 blocks x 256thr (~15 waves/CU), phase2 1024thr/bin (16 waves/CU).
//   Phase 1: bin samples by output row-group (4 rows = 4096 floats per bin,
//            256 bins); dense per-bin record regions claimed via one global
//            atomic per (block,bin). Record (16 B): {colbase, u=w2a*s,
//            v=w2b*s, w3enc}. Integral floor==ceil double-count folded into
//            w2a / w3enc==2.0. Row-pair straddling a bin -> 2 records.
//   Phase 2: one block per bin; ds_add_f32 into a 4-row LDS tile (+1 row
//            margin absorbs weight-0 edge adds), coalesced float4 write.
//            Tiles cover y exactly -> no y memset.

#define IN_DIM   1024
#define OUT_COLS 1024
#define NBINS    256
#define CAP      4096                 // records/bin (expect ~2441, >30 sigma headroom)
#define P1T      256                  // phase-1 threads
#define SPB      512                  // samples per phase-1 block -> 977 blocks
#define SPT      (SPB / P1T)          // samples per thread per pass (2)
#define P2T      1024                 // phase-2 threads
#define TILE_F   4096                 // 4 rows * 1024 cols
#define TILE_PAD (TILE_F + OUT_COLS + 8)

__global__ __launch_bounds__(P1T) void hl_phase1(
    const float*  __restrict__ x,
    const float4* __restrict__ ri,
    const float*  __restrict__ vals,
    int4*         __restrict__ recbuf,   // [NBINS * CAP]
    int*          __restrict__ gctr,     // [NBINS], pre-zeroed
    int n)
{
    __shared__ int hist[NBINS];
    __shared__ int base[NBINS];
    __shared__ int cur[NBINS];
    const int tid = threadIdx.x;
    hist[tid] = 0; cur[tid] = 0;          // P1T == NBINS
    __syncthreads();

    const int i0 = blockIdx.x * SPB;
    const float* rif = (const float*)ri;  // scalar view for pass 1 (.z only)

    // pass 1: count records per bin
    #pragma unroll
    for (int s = 0; s < SPT; ++s) {
        int i = i0 + s * P1T + tid;
        if (i < n) {
            float rz = rif[4 * i + 2];
            int if2 = (int)floorf(rz);
            int ic2 = (int)ceilf(rz);
            int b0 = if2 >> 2, b1 = ic2 >> 2;
            atomicAdd(&hist[b0], 1);
            if (b1 != b0) atomicAdd(&hist[b1], 1);
        }
    }
    __syncthreads();

    // claim dense per-bin regions: one global atomic per (block,bin)
    {
        int h = hist[tid];
        base[tid] = h ? atomicAdd(&gctr[tid], h) : 0;
    }
    __syncthreads();

    // pass 2: full compute + emit records (ri re-read is L2-warm from pass 1)
    #pragma unroll
    for (int s = 0; s < SPT; ++s) {
        int i = i0 + s * P1T + tid;
        if (i >= n) continue;
        float4 r  = ri[i];
        float val = vals[i];

        float f0 = floorf(r.x), c0 = ceilf(r.x);
        float f1 = floorf(r.y), c1 = ceilf(r.y);
        float f2 = floorf(r.z), c2 = ceilf(r.z);
        float f3 = floorf(r.w), c3 = ceilf(r.w);
        float wf0 = 1.f - (r.x - f0), wc0 = 1.f - (c0 - r.x);
        float wf1 = 1.f - (r.y - f1), wc1 = 1.f - (c1 - r.y);
        float wf2 = 1.f - (r.z - f2), wc2 = 1.f - (c2 - r.z);
        float wf3 = 1.f - (r.w - f3);
        int if0=(int)f0, ic0=(int)c0, if1=(int)f1, ic1=(int)c1;
        int if2=(int)f2, ic2=(int)c2, if3=(int)f3, ic3=(int)c3;

        const float* xr0 = x + if0 * IN_DIM;
        const float* xr1 = x + ic0 * IN_DIM;
        float s_ = wf0 * (wf1 * xr0[if1] + wc1 * xr0[ic1])
                 + wc0 * (wf1 * xr1[if1] + wc1 * xr1[ic1]);
        s_ *= val;

        float w2a, w2b;
        if (ic2 == if2) { w2a = wf2 + wc2; w2b = 0.f; }
        else            { w2a = wf2;       w2b = wc2; }
        float w3enc = (ic3 == if3) ? 2.0f : wf3;   // decode: 2->(2,0), w->(w,1-w)

        int b0 = if2 >> 2, b1 = ic2 >> 2;
        {
            int rank = atomicAdd(&cur[b0], 1);
            int slot = base[b0] + rank;
            if (slot < CAP) {
                int4 rec;
                rec.x = if2 * OUT_COLS + if3;
                rec.y = __float_as_int(w2a * s_);
                rec.z = __float_as_int((b1 == b0) ? w2b * s_ : 0.f);
                rec.w = __float_as_int(w3enc);
                recbuf[b0 * CAP + slot] = rec;
            }
        }
        if (b1 != b0) {
            int rank = atomicAdd(&cur[b1], 1);
            int slot = base[b1] + rank;
            if (slot < CAP) {
                int4 rec;
                rec.x = ic2 * OUT_COLS + if3;
                rec.y = __float_as_int(w2b * s_);
                rec.z = __float_as_int(0.f);
                rec.w = __float_as_int(w3enc);
                recbuf[b1 * CAP + slot] = rec;
            }
        }
    }
}

__global__ __launch_bounds__(P2T) void hl_phase2(
    const int4* __restrict__ recbuf,
    const int*  __restrict__ gctr,
    float*      __restrict__ y)
{
    __shared__ __align__(16) float tile[TILE_PAD];
    const int bin = blockIdx.x;
    const int tid = threadIdx.x;
    for (int k = tid; k < TILE_PAD; k += P2T) tile[k] = 0.f;
    __syncthreads();

    int count = gctr[bin];
    if (count > CAP) count = CAP;
    const int4* rb = recbuf + bin * CAP;
    const int tilebase = bin * TILE_F;

    for (int j = tid; j < count; j += P2T) {
        int4 rec = rb[j];
        int   idx = rec.x - tilebase;
        float u   = __int_as_float(rec.y);
        float v   = __int_as_float(rec.z);
        float w3e = __int_as_float(rec.w);
        float w3a, w3b;
        if (w3e == 2.0f) { w3a = 2.0f; w3b = 0.f; }
        else             { w3a = w3e;  w3b = 1.0f - w3e; }
        __hip_atomic_fetch_add(&tile[idx],     u * w3a, __ATOMIC_RELAXED, __HIP_MEMORY_SCOPE_WORKGROUP);
        __hip_atomic_fetch_add(&tile[idx + 1], u * w3b, __ATOMIC_RELAXED, __HIP_MEMORY_SCOPE_WORKGROUP);
        if (v != 0.f) {
            __hip_atomic_fetch_add(&tile[idx + 1024], v * w3a, __ATOMIC_RELAXED, __HIP_MEMORY_SCOPE_WORKGROUP);
            __hip_atomic_fetch_add(&tile[idx + 1025], v * w3b, __ATOMIC_RELAXED, __HIP_MEMORY_SCOPE_WORKGROUP);
        }
    }
    __syncthreads();

    // tiles partition y exactly: plain coalesced stores, no memset needed
    float4* y4 = (float4*)y + bin * (TILE_F / 4);
    const float4* t4 = (const float4*)tile;
    for (int k = tid; k < TILE_F / 4; k += P2T) y4[k] = t4[k];
}

// ---- fallback (ws too small): direct-atomic kernel ----
__global__ __launch_bounds__(256) void hl_direct(
    const float* __restrict__ x, const float4* __restrict__ ri,
    const float* __restrict__ vals, float* __restrict__ y, int n)
{
    int i = blockIdx.x * blockDim.x + threadIdx.x;
    if (i >= n) return;
    float4 r = ri[i];
    float val = vals[i];
    float f0 = floorf(r.x), c0 = ceilf(r.x);
    float f1 = floorf(r.y), c1 = ceilf(r.y);
    float f2 = floorf(r.z), c2 = ceilf(r.z);
    float f3 = floorf(r.w), c3 = ceilf(r.w);
    float wf0 = 1.f-(r.x-f0), wc0 = 1.f-(c0-r.x);
    float wf1 = 1.f-(r.y-f1), wc1 = 1.f-(c1-r.y);
    float wf2 = 1.f-(r.z-f2), wc2 = 1.f-(c2-r.z);
    float wf3 = 1.f-(r.w-f3), wc3 = 1.f-(c3-r.w);
    int if0=(int)f0, ic0=(int)c0, if1=(int)f1, ic1=(int)c1;
    int if2=(int)f2, ic2=(int)c2, if3=(int)f3, ic3=(int)c3;
    const float* xr0 = x + if0 * IN_DIM;
    const float* xr1 = x + ic0 * IN_DIM;
    float s = wf0*(wf1*xr0[if1]+wc1*xr0[ic1]) + wc0*(wf1*xr1[if1]+wc1*xr1[ic1]);
    s *= val;
    float* y2 = y + if2 * OUT_COLS;
    float* y3 = y + ic2 * OUT_COLS;
    unsafeAtomicAdd(y2 + if3, wf2*wf3*s);
    unsafeAtomicAdd(y2 + ic3, wf2*wc3*s);
    unsafeAtomicAdd(y3 + if3, wc2*wf3*s);
    unsafeAtomicAdd(y3 + ic3, wc2*wc3*s);
}

extern "C" void kernel_launch(void* const* d_in, const int* in_sizes, int n_in,
                              void* d_out, int out_size, void* d_ws, size_t ws_size,
                              hipStream_t stream) {
    const float*  x    = (const float*)d_in[0];
    const float4* ri   = (const float4*)d_in[1];
    const float*  vals = (const float*)d_in[2];
    float*        y    = (float*)d_out;
    int n = in_sizes[2];  // N = 500000

    const size_t REQ = 1024 + (size_t)NBINS * CAP * sizeof(int4);  // ~16.8 MB
    if (ws_size >= REQ) {
        int*  gctr   = (int*)d_ws;
        int4* recbuf = (int4*)((char*)d_ws + 1024);
        hipMemsetAsync(d_ws, 0, 1024, stream);   // zero bin counters
        int grid1 = (n + SPB - 1) / SPB;
        hl_phase1<<<grid1, P1T, 0, stream>>>(x, ri, vals, recbuf, gctr, n);
        hl_phase2<<<NBINS, P2T, 0, stream>>>(recbuf, gctr, y);
    } else {
        hipMemsetAsync(y, 0, (size_t)out_size * sizeof(float), stream);
        int grid = (n + 255) / 256;
        hl_direct<<<grid, 256, 0, stream>>>(x, ri, vals, y, n);
    }
}

// Round 5
// 95.389 us; speedup vs baseline: 1.1800x; 1.1800x over previous
//
#include <hip/hip_runtime.h>

// HyperLayer, R5: two-phase binned scatter.
// R4 post-mortem: 977 blocks -> 977*256=250k region-claim atomics (vs R3's
// 63k); at the ~19G/s memory-side atomic ceiling that's the +13us regression.
// Block count is an atomic-cost knob. R5: back to 245 blocks (63k claims) but
// 1024 threads/block (16 waves/CU, 2x R3's phase1 occupancy), and samples
// (ri, vals) held in registers between pass 1 and pass 2 (no ri re-read).
//   Phase 1: bin samples by output row-group (4 rows = 4096 floats, 256
//            bins); dense per-bin regions claimed via one global atomic per
//            (block,bin). Record (16 B): {colbase, u=w2a*s, v=w2b*s, w3enc}.
//            Integral floor==ceil double-count folded into w2a / w3enc==2.0.
//            Row pair straddling a bin boundary -> 2 records.
//   Phase 2: one block per bin; ds_add_f32 into a 4-row LDS tile (+1 row
//            margin absorbs weight-0 edge adds), coalesced float4 writes.
//            Tiles cover y exactly -> no y memset.

#define IN_DIM   1024
#define OUT_COLS 1024
#define NBINS    256
#define CAP      4096                 // records/bin (expect ~2441, >30 sigma headroom)
#define P1T      1024                 // phase-1 threads
#define SPB      2048                 // samples per phase-1 block -> 245 blocks
#define SPT      (SPB / P1T)          // samples per thread (2)
#define P2T      1024                 // phase-2 threads
#define TILE_F   4096                 // 4 rows * 1024 cols
#define TILE_PAD (TILE_F + OUT_COLS + 8)

__global__ __launch_bounds__(P1T) void hl_phase1(
    const float*  __restrict__ x,
    const float4* __restrict__ ri,
    const float*  __restrict__ vals,
    int4*         __restrict__ recbuf,   // [NBINS * CAP]
    int*          __restrict__ gctr,     // [NBINS], pre-zeroed
    int n)
{
    __shared__ int hist[NBINS];
    __shared__ int base[NBINS];
    __shared__ int cur[NBINS];
    const int tid = threadIdx.x;
    if (tid < NBINS) { hist[tid] = 0; cur[tid] = 0; }
    __syncthreads();

    const int i0 = blockIdx.x * SPB;

    // pass 1: load samples into registers, count records per bin
    float4 rreg[SPT];
    float  vreg[SPT];
    #pragma unroll
    for (int s = 0; s < SPT; ++s) {
        int i = i0 + s * P1T + tid;
        if (i < n) {
            float4 r = ri[i];
            rreg[s] = r;
            vreg[s] = vals[i];
            int if2 = (int)floorf(r.z);
            int ic2 = (int)ceilf(r.z);
            int b0 = if2 >> 2, b1 = ic2 >> 2;
            atomicAdd(&hist[b0], 1);
            if (b1 != b0) atomicAdd(&hist[b1], 1);
        }
    }
    __syncthreads();

    // claim dense per-bin regions: one global atomic per (block,bin)
    if (tid < NBINS) {
        int h = hist[tid];
        base[tid] = h ? atomicAdd(&gctr[tid], h) : 0;
    }
    __syncthreads();

    // pass 2: full compute + emit records (samples already in registers)
    #pragma unroll
    for (int s = 0; s < SPT; ++s) {
        int i = i0 + s * P1T + tid;
        if (i >= n) continue;
        float4 r  = rreg[s];
        float val = vreg[s];

        float f0 = floorf(r.x), c0 = ceilf(r.x);
        float f1 = floorf(r.y), c1 = ceilf(r.y);
        float f2 = floorf(r.z), c2 = ceilf(r.z);
        float f3 = floorf(r.w), c3 = ceilf(r.w);
        float wf0 = 1.f - (r.x - f0), wc0 = 1.f - (c0 - r.x);
        float wf1 = 1.f - (r.y - f1), wc1 = 1.f - (c1 - r.y);
        float wf2 = 1.f - (r.z - f2), wc2 = 1.f - (c2 - r.z);
        float wf3 = 1.f - (r.w - f3);
        int if0=(int)f0, ic0=(int)c0, if1=(int)f1, ic1=(int)c1;
        int if2=(int)f2, ic2=(int)c2, if3=(int)f3, ic3=(int)c3;

        const float* xr0 = x + if0 * IN_DIM;
        const float* xr1 = x + ic0 * IN_DIM;
        float s_ = wf0 * (wf1 * xr0[if1] + wc1 * xr0[ic1])
                 + wc0 * (wf1 * xr1[if1] + wc1 * xr1[ic1]);
        s_ *= val;

        float w2a, w2b;
        if (ic2 == if2) { w2a = wf2 + wc2; w2b = 0.f; }
        else            { w2a = wf2;       w2b = wc2; }
        float w3enc = (ic3 == if3) ? 2.0f : wf3;   // decode: 2->(2,0), w->(w,1-w)

        int b0 = if2 >> 2, b1 = ic2 >> 2;
        {
            int rank = atomicAdd(&cur[b0], 1);
            int slot = base[b0] + rank;
            if (slot < CAP) {
                int4 rec;
                rec.x = if2 * OUT_COLS + if3;
                rec.y = __float_as_int(w2a * s_);
                rec.z = __float_as_int((b1 == b0) ? w2b * s_ : 0.f);
                rec.w = __float_as_int(w3enc);
                recbuf[b0 * CAP + slot] = rec;
            }
        }
        if (b1 != b0) {
            int rank = atomicAdd(&cur[b1], 1);
            int slot = base[b1] + rank;
            if (slot < CAP) {
                int4 rec;
                rec.x = ic2 * OUT_COLS + if3;
                rec.y = __float_as_int(w2b * s_);
                rec.z = __float_as_int(0.f);
                rec.w = __float_as_int(w3enc);
                recbuf[b1 * CAP + slot] = rec;
            }
        }
    }
}

__global__ __launch_bounds__(P2T) void hl_phase2(
    const int4* __restrict__ recbuf,
    const int*  __restrict__ gctr,
    float*      __restrict__ y)
{
    __shared__ __align__(16) float tile[TILE_PAD];
    const int bin = blockIdx.x;
    const int tid = threadIdx.x;
    for (int k = tid; k < TILE_PAD; k += P2T) tile[k] = 0.f;
    __syncthreads();

    int count = gctr[bin];
    if (count > CAP) count = CAP;
    const int4* rb = recbuf + bin * CAP;
    const int tilebase = bin * TILE_F;

    for (int j = tid; j < count; j += P2T) {
        int4 rec = rb[j];
        int   idx = rec.x - tilebase;
        float u   = __int_as_float(rec.y);
        float v   = __int_as_float(rec.z);
        float w3e = __int_as_float(rec.w);
        float w3a, w3b;
        if (w3e == 2.0f) { w3a = 2.0f; w3b = 0.f; }
        else             { w3a = w3e;  w3b = 1.0f - w3e; }
        __hip_atomic_fetch_add(&tile[idx],     u * w3a, __ATOMIC_RELAXED, __HIP_MEMORY_SCOPE_WORKGROUP);
        __hip_atomic_fetch_add(&tile[idx + 1], u * w3b, __ATOMIC_RELAXED, __HIP_MEMORY_SCOPE_WORKGROUP);
        if (v != 0.f) {
            __hip_atomic_fetch_add(&tile[idx + 1024], v * w3a, __ATOMIC_RELAXED, __HIP_MEMORY_SCOPE_WORKGROUP);
            __hip_atomic_fetch_add(&tile[idx + 1025], v * w3b, __ATOMIC_RELAXED, __HIP_MEMORY_SCOPE_WORKGROUP);
        }
    }
    __syncthreads();

    // tiles partition y exactly: plain coalesced stores, no memset needed
    float4* y4 = (float4*)y + bin * (TILE_F / 4);
    const float4* t4 = (const float4*)tile;
    for (int k = tid; k < TILE_F / 4; k += P2T) y4[k] = t4[k];
}

// ---- fallback (ws too small): direct-atomic kernel ----
__global__ __launch_bounds__(256) void hl_direct(
    const float* __restrict__ x, const float4* __restrict__ ri,
    const float* __restrict__ vals, float* __restrict__ y, int n)
{
    int i = blockIdx.x * blockDim.x + threadIdx.x;
    if (i >= n) return;
    float4 r = ri[i];
    float val = vals[i];
    float f0 = floorf(r.x), c0 = ceilf(r.x);
    float f1 = floorf(r.y), c1 = ceilf(r.y);
    float f2 = floorf(r.z), c2 = ceilf(r.z);
    float f3 = floorf(r.w), c3 = ceilf(r.w);
    float wf0 = 1.f-(r.x-f0), wc0 = 1.f-(c0-r.x);
    float wf1 = 1.f-(r.y-f1), wc1 = 1.f-(c1-r.y);
    float wf2 = 1.f-(r.z-f2), wc2 = 1.f-(c2-r.z);
    float wf3 = 1.f-(r.w-f3), wc3 = 1.f-(c3-r.w);
    int if0=(int)f0, ic0=(int)c0, if1=(int)f1, ic1=(int)c1;
    int if2=(int)f2, ic2=(int)c2, if3=(int)f3, ic3=(int)c3;
    const float* xr0 = x + if0 * IN_DIM;
    const float* xr1 = x + ic0 * IN_DIM;
    float s = wf0*(wf1*xr0[if1]+wc1*xr0[ic1]) + wc0*(wf1*xr1[if1]+wc1*xr1[ic1]);
    s *= val;
    float* y2 = y + if2 * OUT_COLS;
    float* y3 = y + ic2 * OUT_COLS;
    unsafeAtomicAdd(y2 + if3, wf2*wf3*s);
    unsafeAtomicAdd(y2 + ic3, wf2*wc3*s);
    unsafeAtomicAdd(y3 + if3, wc2*wf3*s);
    unsafeAtomicAdd(y3 + ic3, wc2*wc3*s);
}

extern "C" void kernel_launch(void* const* d_in, const int* in_sizes, int n_in,
                              void* d_out, int out_size, void* d_ws, size_t ws_size,
                              hipStream_t stream) {
    const float*  x    = (const float*)d_in[0];
    const float4* ri   = (const float4*)d_in[1];
    const float*  vals = (const float*)d_in[2];
    float*        y    = (float*)d_out;
    int n = in_sizes[2];  // N = 500000

    const size_t REQ = 1024 + (size_t)NBINS * CAP * sizeof(int4);  // ~16.8 MB
    if (ws_size >= REQ) {
        int*  gctr   = (int*)d_ws;
        int4* recbuf = (int4*)((char*)d_ws + 1024);
        hipMemsetAsync(d_ws, 0, 1024, stream);   // zero bin counters
        int grid1 = (n + SPB - 1) / SPB;
        hl_phase1<<<grid1, P1T, 0, stream>>>(x, ri, vals, recbuf, gctr, n);
        hl_phase2<<<NBINS, P2T, 0, stream>>>(recbuf, gctr, y);
    } else {
        hipMemsetAsync(y, 0, (size_t)out_size * sizeof(float), stream);
        int grid = (n + 255) / 256;
        hl_direct<<<grid, 256, 0, stream>>>(x, ri, vals, y, n);
    }
}

// Round 6
// 94.727 us; speedup vs baseline: 1.1882x; 1.0070x over previous
//
#include <hip/hip_runtime.h>

// HyperLayer, R6: two-phase binned scatter.
// R5 post-mortem: total 95.4us; ~45us is fixed harness poison fills, ~50us is
// phase1+phase2 vs ~6us traffic floor => transaction/latency-bound.
// R6 changes (phase 1):
//  (a) 64B-aligned per-(block,bin) record regions: claims rounded up to 4
//      records (one line), <=3 zero-pad records written by the claiming
//      thread. Kills cross-XCD false sharing / partial-line RMW on recbuf.
//  (b) x-gather prefetched in pass 1 (raw 4 floats held in VGPRs); L2 latency
//      hides behind hist atomics + barrier + claim instead of stalling pass 2.
//   Phase 1: bin samples by output row-group (4 rows = 4096 floats, 256
//            bins); dense per-bin regions claimed via one global atomic per
//            (block,bin). Record (16 B): {colbase, u=w2a*s, v=w2b*s, w3enc}.
//            Integral floor==ceil double-count folded into w2a / w3enc==2.0.
//            Row pair straddling a bin boundary -> 2 records.
//   Phase 2: one block per bin; ds_add_f32 into a 4-row LDS tile (+1 row
//            margin absorbs weight-0 edge adds), coalesced float4 writes.
//            Tiles cover y exactly -> no y memset.

#define IN_DIM   1024
#define OUT_COLS 1024
#define NBINS    256
#define CAP      4096                 // records/bin (expect ~2810 incl pad)
#define P1T      1024                 // phase-1 threads
#define SPB      2048                 // samples per phase-1 block -> 245 blocks
#define SPT      (SPB / P1T)          // samples per thread (2)
#define P2T      1024                 // phase-2 threads
#define TILE_F   4096                 // 4 rows * 1024 cols
#define TILE_PAD (TILE_F + OUT_COLS + 8)

__global__ __launch_bounds__(P1T) void hl_phase1(
    const float*  __restrict__ x,
    const float4* __restrict__ ri,
    const float*  __restrict__ vals,
    int4*         __restrict__ recbuf,   // [NBINS * CAP]
    int*          __restrict__ gctr,     // [NBINS], pre-zeroed
    int n)
{
    __shared__ int hist[NBINS];
    __shared__ int base[NBINS];
    __shared__ int cur[NBINS];
    const int tid = threadIdx.x;
    if (tid < NBINS) { hist[tid] = 0; cur[tid] = 0; }
    __syncthreads();

    const int i0 = blockIdx.x * SPB;

    // pass 1: load samples into registers, ISSUE the x-gather (consumed in
    // pass 2 -- latency hides behind hist/claim), count records per bin.
    float4 rreg[SPT];
    float  vreg[SPT];
    float  x00[SPT], x01[SPT], x10[SPT], x11[SPT];
    #pragma unroll
    for (int s = 0; s < SPT; ++s) {
        int i = i0 + s * P1T + tid;
        if (i < n) {
            float4 r = ri[i];
            rreg[s] = r;
            vreg[s] = vals[i];
            int if0 = (int)floorf(r.x), ic0 = (int)ceilf(r.x);
            int if1 = (int)floorf(r.y), ic1 = (int)ceilf(r.y);
            const float* xr0 = x + if0 * IN_DIM;
            const float* xr1 = x + ic0 * IN_DIM;
            x00[s] = xr0[if1]; x01[s] = xr0[ic1];
            x10[s] = xr1[if1]; x11[s] = xr1[ic1];
            int if2 = (int)floorf(r.z);
            int ic2 = (int)ceilf(r.z);
            int b0 = if2 >> 2, b1 = ic2 >> 2;
            atomicAdd(&hist[b0], 1);
            if (b1 != b0) atomicAdd(&hist[b1], 1);
        }
    }
    __syncthreads();

    // claim 64B-aligned dense per-bin regions: one global atomic per
    // (block,bin), size rounded to 4 records (1 line); zero-pad the tail.
    if (tid < NBINS) {
        int h = hist[tid];
        int b = 0;
        if (h) {
            int h4 = (h + 3) & ~3;
            b = atomicAdd(&gctr[tid], h4);
            int4 z;                       // benign record: adds exact 0.0
            z.x = tid * TILE_F;           // idx -> tile[0]
            z.y = 0; z.z = 0;
            z.w = __float_as_int(1.0f);
            for (int k = h; k < h4; ++k) {
                int slot = b + k;
                if (slot < CAP) recbuf[tid * CAP + slot] = z;
            }
        }
        base[tid] = b;
    }
    __syncthreads();

    // pass 2: weights + emit records (samples & gathered x already in regs)
    #pragma unroll
    for (int s = 0; s < SPT; ++s) {
        int i = i0 + s * P1T + tid;
        if (i >= n) continue;
        float4 r  = rreg[s];
        float val = vreg[s];

        float f0 = floorf(r.x), c0 = ceilf(r.x);
        float f1 = floorf(r.y), c1 = ceilf(r.y);
        float f2 = floorf(r.z), c2 = ceilf(r.z);
        float f3 = floorf(r.w), c3 = ceilf(r.w);
        float wf0 = 1.f - (r.x - f0), wc0 = 1.f - (c0 - r.x);
        float wf1 = 1.f - (r.y - f1), wc1 = 1.f - (c1 - r.y);
        float wf2 = 1.f - (r.z - f2), wc2 = 1.f - (c2 - r.z);
        float wf3 = 1.f - (r.w - f3);
        int if2=(int)f2, ic2=(int)c2, if3=(int)f3, ic3=(int)c3;

        float s_ = wf0 * (wf1 * x00[s] + wc1 * x01[s])
                 + wc0 * (wf1 * x10[s] + wc1 * x11[s]);
        s_ *= val;

        float w2a, w2b;
        if (ic2 == if2) { w2a = wf2 + wc2; w2b = 0.f; }
        else            { w2a = wf2;       w2b = wc2; }
        float w3enc = (ic3 == if3) ? 2.0f : wf3;   // decode: 2->(2,0), w->(w,1-w)

        int b0 = if2 >> 2, b1 = ic2 >> 2;
        {
            int rank = atomicAdd(&cur[b0], 1);
            int slot = base[b0] + rank;
            if (slot < CAP) {
                int4 rec;
                rec.x = if2 * OUT_COLS + if3;
                rec.y = __float_as_int(w2a * s_);
                rec.z = __float_as_int((b1 == b0) ? w2b * s_ : 0.f);
                rec.w = __float_as_int(w3enc);
                recbuf[b0 * CAP + slot] = rec;
            }
        }
        if (b1 != b0) {
            int rank = atomicAdd(&cur[b1], 1);
            int slot = base[b1] + rank;
            if (slot < CAP) {
                int4 rec;
                rec.x = ic2 * OUT_COLS + if3;
                rec.y = __float_as_int(w2b * s_);
                rec.z = __float_as_int(0.f);
                rec.w = __float_as_int(w3enc);
                recbuf[b1 * CAP + slot] = rec;
            }
        }
    }
}

__global__ __launch_bounds__(P2T) void hl_phase2(
    const int4* __restrict__ recbuf,
    const int*  __restrict__ gctr,
    float*      __restrict__ y)
{
    __shared__ __align__(16) float tile[TILE_PAD];
    const int bin = blockIdx.x;
    const int tid = threadIdx.x;
    for (int k = tid; k < TILE_PAD; k += P2T) tile[k] = 0.f;
    __syncthreads();

    int count = gctr[bin];
    if (count > CAP) count = CAP;
    const int4* rb = recbuf + bin * CAP;
    const int tilebase = bin * TILE_F;

    for (int j = tid; j < count; j += P2T) {
        int4 rec = rb[j];
        int   idx = rec.x - tilebase;
        float u   = __int_as_float(rec.y);
        float v   = __int_as_float(rec.z);
        float w3e = __int_as_float(rec.w);
        float w3a, w3b;
        if (w3e == 2.0f) { w3a = 2.0f; w3b = 0.f; }
        else             { w3a = w3e;  w3b = 1.0f - w3e; }
        __hip_atomic_fetch_add(&tile[idx],     u * w3a, __ATOMIC_RELAXED, __HIP_MEMORY_SCOPE_WORKGROUP);
        __hip_atomic_fetch_add(&tile[idx + 1], u * w3b, __ATOMIC_RELAXED, __HIP_MEMORY_SCOPE_WORKGROUP);
        if (v != 0.f) {
            __hip_atomic_fetch_add(&tile[idx + 1024], v * w3a, __ATOMIC_RELAXED, __HIP_MEMORY_SCOPE_WORKGROUP);
            __hip_atomic_fetch_add(&tile[idx + 1025], v * w3b, __ATOMIC_RELAXED, __HIP_MEMORY_SCOPE_WORKGROUP);
        }
    }
    __syncthreads();

    // tiles partition y exactly: plain coalesced stores, no memset needed
    float4* y4 = (float4*)y + bin * (TILE_F / 4);
    const float4* t4 = (const float4*)tile;
    for (int k = tid; k < TILE_F / 4; k += P2T) y4[k] = t4[k];
}

// ---- fallback (ws too small): direct-atomic kernel ----
__global__ __launch_bounds__(256) void hl_direct(
    const float* __restrict__ x, const float4* __restrict__ ri,
    const float* __restrict__ vals, float* __restrict__ y, int n)
{
    int i = blockIdx.x * blockDim.x + threadIdx.x;
    if (i >= n) return;
    float4 r = ri[i];
    float val = vals[i];
    float f0 = floorf(r.x), c0 = ceilf(r.x);
    float f1 = floorf(r.y), c1 = ceilf(r.y);
    float f2 = floorf(r.z), c2 = ceilf(r.z);
    float f3 = floorf(r.w), c3 = ceilf(r.w);
    float wf0 = 1.f-(r.x-f0), wc0 = 1.f-(c0-r.x);
    float wf1 = 1.f-(r.y-f1), wc1 = 1.f-(c1-r.y);
    float wf2 = 1.f-(r.z-f2), wc2 = 1.f-(c2-r.z);
    float wf3 = 1.f-(r.w-f3), wc3 = 1.f-(c3-r.w);
    int if0=(int)f0, ic0=(int)c0, if1=(int)f1, ic1=(int)c1;
    int if2=(int)f2, ic2=(int)c2, if3=(int)f3, ic3=(int)c3;
    const float* xr0 = x + if0 * IN_DIM;
    const float* xr1 = x + ic0 * IN_DIM;
    float s = wf0*(wf1*xr0[if1]+wc1*xr0[ic1]) + wc0*(wf1*xr1[if1]+wc1*xr1[ic1]);
    s *= val;
    float* y2 = y + if2 * OUT_COLS;
    float* y3 = y + ic2 * OUT_COLS;
    unsafeAtomicAdd(y2 + if3, wf2*wf3*s);
    unsafeAtomicAdd(y2 + ic3, wf2*wc3*s);
    unsafeAtomicAdd(y3 + if3, wc2*wf3*s);
    unsafeAtomicAdd(y3 + ic3, wc2*wc3*s);
}

extern "C" void kernel_launch(void* const* d_in, const int* in_sizes, int n_in,
                              void* d_out, int out_size, void* d_ws, size_t ws_size,
                              hipStream_t stream) {
    const float*  x    = (const float*)d_in[0];
    const float4* ri   = (const float4*)d_in[1];
    const float*  vals = (const float*)d_in[2];
    float*        y    = (float*)d_out;
    int n = in_sizes[2];  // N = 500000

    const size_t REQ = 1024 + (size_t)NBINS * CAP * sizeof(int4);  // ~16.8 MB
    if (ws_size >= REQ) {
        int*  gctr   = (int*)d_ws;
        int4* recbuf = (int4*)((char*)d_ws + 1024);
        hipMemsetAsync(d_ws, 0, 1024, stream);   // zero bin counters
        int grid1 = (n + SPB - 1) / SPB;
        hl_phase1<<<grid1, P1T, 0, stream>>>(x, ri, vals, recbuf, gctr, n);
        hl_phase2<<<NBINS, P2T, 0, stream>>>(recbuf, gctr, y);
    } else {
        hipMemsetAsync(y, 0, (size_t)out_size * sizeof(float), stream);
        int grid = (n + 255) / 256;
        hl_direct<<<grid, 256, 0, stream>>>(x, ri, vals, y, n);
    }
}